// Round 2
// baseline (486.869 us; speedup 1.0000x reference)
//
#include <hip/hip_runtime.h>
#include <hip/hip_bf16.h>
#include <cstdint>

// ---------------------------------------------------------------------------
// DGNN pipeline, fp32, CSR-based aggregation (no scatter atomics on features).
// Biases gcn_b / dcn_b cancel inside the following batchnorms (per-channel
// additive shift -> mean shifts identically, variance unchanged) and are
// skipped.
// R1: scan_kernel rewritten chunk-per-thread (was 93us at 0.18% occupancy:
// 49 sequential 1024-wide scans; now one scan + serial chunk passes).
// ---------------------------------------------------------------------------

// Detect whether edge_index arrived as int64 (high int32 words all zero for
// values < 2^31) or int32 (odd int32 positions are random node ids).
__global__ void detect_kernel(const int* __restrict__ ei32, int* __restrict__ flag) {
    int t = threadIdx.x;
    int v = ei32[2 * t + 1];
    if (v != 0) atomicOr(flag, 1);   // nonzero high-word sample => int32 layout
}

__global__ void convert_kernel(const void* __restrict__ ei, int E,
                               const int* __restrict__ flag,
                               int* __restrict__ rowi, int* __restrict__ coli,
                               int* __restrict__ count) {
    int f = *flag;
    int stride = gridDim.x * blockDim.x;
    for (int e = blockIdx.x * blockDim.x + threadIdx.x; e < E; e += stride) {
        int r, c;
        if (f) {
            r = ((const int*)ei)[e];
            c = ((const int*)ei)[E + e];
        } else {
            r = (int)((const long long*)ei)[e];
            c = (int)((const long long*)ei)[E + e];
        }
        rowi[e] = r;
        coli[e] = c;
        atomicAdd(&count[c], 1);
    }
}

// Chunk-per-thread exclusive prefix sum over counts; also emits dinv = rsqrt(deg+1).
// One block of 1024 threads, thread t owns counts[t*C .. t*C+C).
__global__ void scan_kernel(const int* __restrict__ count, int* __restrict__ base,
                            float* __restrict__ dinv, int n) {
    __shared__ int sm[1024];
    int t = threadIdx.x;
    int C = (n + 1023) >> 10;
    int s0 = t * C;
    int s1 = s0 + C < n ? s0 + C : n;
    int sum = 0;
    for (int i = s0; i < s1; i++) sum += count[i];
    sm[t] = sum;
    __syncthreads();
    for (int off = 1; off < 1024; off <<= 1) {
        int add = (t >= off) ? sm[t - off] : 0;
        __syncthreads();
        sm[t] += add;
        __syncthreads();
    }
    int run = sm[t] - sum;   // exclusive prefix of this thread's chunk
    for (int i = s0; i < s1; i++) {
        int v = count[i];
        base[i] = run;
        dinv[i] = rsqrtf((float)(v + 1));   // +1 self loop; always > 0
        run += v;
    }
}

__global__ void scatter_kernel(const int* __restrict__ rowi, const int* __restrict__ coli,
                               const int* __restrict__ base, int* __restrict__ cursor,
                               int* __restrict__ esrc, int E) {
    int stride = gridDim.x * blockDim.x;
    for (int e = blockIdx.x * blockDim.x + threadIdx.x; e < E; e += stride) {
        int c = coli[e];
        int pos = base[c] + atomicAdd(&cursor[c], 1);
        esrc[pos] = rowi[e];
    }
}

// Y[N][128] = X[N][128] @ W[128][128], fp32. W staged in LDS (64 KiB).
// Block: 256 threads; 8 rows per iteration; thread t -> row t/32, cols 4*(t%32)..+3.
__global__ __launch_bounds__(256) void gemm128_kernel(const float* __restrict__ X,
                                                      const float* __restrict__ W,
                                                      float* __restrict__ Y, int n) {
    __shared__ float Wl[128 * 128];
    int t = threadIdx.x;
    for (int i = t * 4; i < 128 * 128; i += 1024) {
        *(float4*)&Wl[i] = *(const float4*)&W[i];
    }
    __syncthreads();
    int rl = t >> 5;           // 0..7
    int c4 = (t & 31) * 4;     // column base
    for (int r0 = blockIdx.x * 8; r0 < n; r0 += gridDim.x * 8) {
        int r = r0 + rl;
        if (r < n) {
            float4 acc = {0.f, 0.f, 0.f, 0.f};
            const float* xr = &X[(size_t)r * 128];
            for (int k = 0; k < 128; k += 4) {
                float4 xv = *(const float4*)&xr[k];   // broadcast across 32 lanes
                float4 w0 = *(float4*)&Wl[(k + 0) * 128 + c4];
                acc.x += xv.x * w0.x; acc.y += xv.x * w0.y; acc.z += xv.x * w0.z; acc.w += xv.x * w0.w;
                float4 w1 = *(float4*)&Wl[(k + 1) * 128 + c4];
                acc.x += xv.y * w1.x; acc.y += xv.y * w1.y; acc.z += xv.y * w1.z; acc.w += xv.y * w1.w;
                float4 w2 = *(float4*)&Wl[(k + 2) * 128 + c4];
                acc.x += xv.z * w2.x; acc.y += xv.z * w2.y; acc.z += xv.z * w2.z; acc.w += xv.z * w2.w;
                float4 w3 = *(float4*)&Wl[(k + 3) * 128 + c4];
                acc.x += xv.w * w3.x; acc.y += xv.w * w3.y; acc.z += xv.w * w3.z; acc.w += xv.w * w3.w;
            }
            *(float4*)&Y[(size_t)r * 128 + c4] = acc;
        }
    }
}

// One wave per node: out[n][c] = dinv[n]*( sum_src dinv[src]*XW[src][c] + dinv[n]*XW[n][c] )
__global__ void prop_kernel(const float* __restrict__ XW, const int* __restrict__ base,
                            const int* __restrict__ count, const int* __restrict__ esrc,
                            const float* __restrict__ dinv, float* __restrict__ out, int n) {
    int wave = (int)((blockIdx.x * blockDim.x + threadIdx.x) >> 6);
    int lane = threadIdx.x & 63;
    if (wave >= n) return;
    int b = base[wave];
    int cnt = count[wave];
    float din = dinv[wave];
    const float2* xw2 = (const float2*)XW;
    float2 acc = {0.f, 0.f};
    for (int i = 0; i < cnt; i++) {
        int src = esrc[b + i];
        float w = dinv[src];
        float2 v = xw2[(size_t)src * 64 + lane];
        acc.x += w * v.x;
        acc.y += w * v.y;
    }
    float2 vs = xw2[(size_t)wave * 64 + lane];
    acc.x = din * (acc.x + din * vs.x);
    acc.y = din * (acc.y + din * vs.y);
    ((float2*)out)[(size_t)wave * 64 + lane] = acc;
}

// Per-channel sum / sumsq over rows; optional elementwise gate M <- M*H first.
__global__ void stats_kernel(float* __restrict__ M, const float* __restrict__ H,
                             float* __restrict__ sums, float* __restrict__ sumsq,
                             int n, int gate) {
    int t = threadIdx.x;
    int col = t & 127;
    int rhalf = t >> 7;  // 0..1
    float s = 0.f, s2 = 0.f;
    for (int r = blockIdx.x * 2 + rhalf; r < n; r += gridDim.x * 2) {
        size_t idx = (size_t)r * 128 + col;
        float v = M[idx];
        if (gate) { v = v * H[idx]; M[idx] = v; }
        s += v;
        s2 += v * v;
    }
    __shared__ float ls[256], ls2[256];
    ls[t] = s; ls2[t] = s2;
    __syncthreads();
    if (t < 128) {
        s = ls[t] + ls[t + 128];
        s2 = ls2[t] + ls2[t + 128];
        atomicAdd(&sums[col], s);
        atomicAdd(&sumsq[col], s2);
    }
}

__global__ void bnapply_kernel(const float* __restrict__ M, const float* __restrict__ sums,
                               const float* __restrict__ sumsq,
                               const float* __restrict__ g, const float* __restrict__ bet,
                               float* __restrict__ Hout, int n) {
    size_t total = (size_t)n * 128;
    float invn = 1.f / (float)n;
    for (size_t idx = (size_t)blockIdx.x * blockDim.x + threadIdx.x; idx < total;
         idx += (size_t)gridDim.x * blockDim.x) {
        int col = (int)(idx & 127);
        float mu = sums[col] * invn;
        float var = sumsq[col] * invn - mu * mu;
        float a = g[col] * rsqrtf(var + 1e-5f);
        float b = bet[col] - mu * a;
        Hout[idx] = M[idx] * a + b;
    }
}

// result[n] = dot(h[n], ow[0:128]) + dot(BN3(gated[n]), ow[128:256]) + ob
__global__ void final_kernel(const float* __restrict__ H, const float* __restrict__ G,
                             const float* __restrict__ sums3, const float* __restrict__ sumsq3,
                             const float* __restrict__ g3, const float* __restrict__ b3,
                             const float* __restrict__ ow, const float* __restrict__ ob,
                             float* __restrict__ out, int n) {
    int wave = (int)((blockIdx.x * blockDim.x + threadIdx.x) >> 6);
    int lane = threadIdx.x & 63;
    if (wave >= n) return;
    int c0 = 2 * lane, c1 = c0 + 1;
    float invn = 1.f / (float)n;
    float2 h2 = ((const float2*)H)[(size_t)wave * 64 + lane];
    float2 g2 = ((const float2*)G)[(size_t)wave * 64 + lane];
    float mu0 = sums3[c0] * invn;
    float var0 = sumsq3[c0] * invn - mu0 * mu0;
    float a0 = g3[c0] * rsqrtf(var0 + 1e-5f);
    float bb0 = b3[c0] - mu0 * a0;
    float mu1 = sums3[c1] * invn;
    float var1 = sumsq3[c1] * invn - mu1 * mu1;
    float a1 = g3[c1] * rsqrtf(var1 + 1e-5f);
    float bb1 = b3[c1] - mu1 * a1;
    float o0 = g2.x * a0 + bb0;
    float o1 = g2.y * a1 + bb1;
    float partial = h2.x * ow[c0] + h2.y * ow[c1] + o0 * ow[128 + c0] + o1 * ow[128 + c1];
    #pragma unroll
    for (int off = 32; off > 0; off >>= 1) partial += __shfl_down(partial, off);
    if (lane == 0) out[wave] = partial + ob[0];
}

extern "C" void kernel_launch(void* const* d_in, const int* in_sizes, int n_in,
                              void* d_out, int out_size, void* d_ws, size_t ws_size,
                              hipStream_t stream) {
    const float* x     = (const float*)d_in[0];
    const void*  ei    = d_in[1];
    const float* gcn_w = (const float*)d_in[2];
    const float* bn1_g = (const float*)d_in[4];
    const float* bn1_b = (const float*)d_in[5];
    const float* dcn_w = (const float*)d_in[6];
    const float* bn3_g = (const float*)d_in[8];
    const float* bn3_b = (const float*)d_in[9];
    const float* out_w = (const float*)d_in[10];
    const float* out_b = (const float*)d_in[11];
    float* out = (float*)d_out;

    int N = in_sizes[0] / 128;
    int E = in_sizes[1] / 2;
    size_t N128 = (size_t)N * 128;

    float* A     = (float*)d_ws;            // xw / hw           [N*128]
    float* B     = A + N128;                // agg (reused)      [N*128]
    float* H     = B + N128;                // h                 [N*128]
    int*   rowi  = (int*)(H + N128);        // [E]
    int*   coli  = rowi + E;                // [E]
    int*   esrc  = coli + E;                // [E]
    float* dinv  = (float*)(esrc + E);      // [N]
    int*   base  = (int*)(dinv + N);        // [N]
    // ---- zeroed region starts here ----
    int*   count  = base + N;               // [N]
    int*   cursor = count + N;              // [N]
    float* sums1  = (float*)(cursor + N);   // [128]
    float* sumsq1 = sums1 + 128;            // [128]
    float* sums3  = sumsq1 + 128;           // [128]
    float* sumsq3 = sums3 + 128;            // [128]
    int*   flag   = (int*)(sumsq3 + 128);   // [1]

    size_t zero_bytes = (size_t)((char*)(flag + 1) - (char*)count);
    hipMemsetAsync(count, 0, zero_bytes, stream);

    int egrid = (E + 255) / 256;
    if (egrid > 2048) egrid = 2048;
    int pgrid = (N + 3) / 4;   // 4 waves / block, one node per wave

    detect_kernel<<<1, 1024, 0, stream>>>((const int*)ei, flag);
    convert_kernel<<<egrid, 256, 0, stream>>>(ei, E, flag, rowi, coli, count);
    scan_kernel<<<1, 1024, 0, stream>>>(count, base, dinv, N);
    scatter_kernel<<<egrid, 256, 0, stream>>>(rowi, coli, base, cursor, esrc, E);

    gemm128_kernel<<<512, 256, 0, stream>>>(x, gcn_w, A, N);
    prop_kernel<<<pgrid, 256, 0, stream>>>(A, base, count, esrc, dinv, B, N);
    stats_kernel<<<1024, 256, 0, stream>>>(B, nullptr, sums1, sumsq1, N, 0);

    int agrid = (int)((N128 + 255) / 256);
    if (agrid > 4096) agrid = 4096;
    bnapply_kernel<<<agrid, 256, 0, stream>>>(B, sums1, sumsq1, bn1_g, bn1_b, H, N);

    gemm128_kernel<<<512, 256, 0, stream>>>(H, dcn_w, A, N);
    prop_kernel<<<pgrid, 256, 0, stream>>>(A, base, count, esrc, dinv, B, N);
    stats_kernel<<<1024, 256, 0, stream>>>(B, H, sums3, sumsq3, N, 1);

    final_kernel<<<pgrid, 256, 0, stream>>>(H, B, sums3, sumsq3, bn3_g, bn3_b,
                                            out_w, out_b, out, N);
}

// Round 3
// 390.154 us; speedup vs baseline: 1.2479x; 1.2479x over previous
//
#include <hip/hip_runtime.h>
#include <hip/hip_bf16.h>
#include <cstdint>

// ---------------------------------------------------------------------------
// DGNN pipeline, fp32, CSR-based aggregation (no scatter atomics on features).
// Biases gcn_b / dcn_b cancel inside the following batchnorms (per-channel
// additive shift -> mean shifts identically, variance unchanged) and are
// skipped.
// R1: chunk-per-thread single-block scan -> REGRESSED (93->110us): single CU,
//     uncoalesced stride-196B chunk loads, latency-bound.
// R2: 3-kernel multi-block scan (bsum -> scanb -> emit), coalesced int4 loads,
//     49 blocks. Expect ~8us total for the scan path.
// ---------------------------------------------------------------------------

// Detect whether edge_index arrived as int64 (high int32 words all zero for
// values < 2^31) or int32 (odd int32 positions are random node ids).
__global__ void detect_kernel(const int* __restrict__ ei32, int* __restrict__ flag) {
    int t = threadIdx.x;
    int v = ei32[2 * t + 1];
    if (v != 0) atomicOr(flag, 1);   // nonzero high-word sample => int32 layout
}

__global__ void convert_kernel(const void* __restrict__ ei, int E,
                               const int* __restrict__ flag,
                               int* __restrict__ rowi, int* __restrict__ coli,
                               int* __restrict__ count) {
    int f = *flag;
    int stride = gridDim.x * blockDim.x;
    for (int e = blockIdx.x * blockDim.x + threadIdx.x; e < E; e += stride) {
        int r, c;
        if (f) {
            r = ((const int*)ei)[e];
            c = ((const int*)ei)[E + e];
        } else {
            r = (int)((const long long*)ei)[e];
            c = (int)((const long long*)ei)[E + e];
        }
        rowi[e] = r;
        coli[e] = c;
        atomicAdd(&count[c], 1);
    }
}

// ---- 3-phase multi-block exclusive scan over count[N] (N <= 1M) ----
// Phase 1: per-block (1024 elems) partial sums.
__global__ __launch_bounds__(256) void bsum_kernel(const int* __restrict__ count,
                                                   int* __restrict__ bsum, int n) {
    int t = threadIdx.x;
    int i0 = blockIdx.x * 1024 + t * 4;
    int s = 0;
    if (i0 + 4 <= n) {
        int4 v = *(const int4*)&count[i0];
        s = v.x + v.y + v.z + v.w;
    } else {
        for (int i = i0; i < n; i++) s += count[i];
    }
    __shared__ int ls[256];
    ls[t] = s;
    __syncthreads();
    for (int off = 128; off > 0; off >>= 1) {
        if (t < off) ls[t] += ls[t + off];
        __syncthreads();
    }
    if (t == 0) bsum[blockIdx.x] = ls[0];
}

// Phase 2: single-block exclusive scan of the (<=1024) block sums, in place.
__global__ void scanb_kernel(int* __restrict__ bsum, int nb) {
    __shared__ int sm[1024];
    int t = threadIdx.x;
    int v = (t < nb) ? bsum[t] : 0;
    sm[t] = v;
    __syncthreads();
    for (int off = 1; off < 1024; off <<= 1) {
        int a = (t >= off) ? sm[t - off] : 0;
        __syncthreads();
        sm[t] += a;
        __syncthreads();
    }
    if (t < nb) bsum[t] = sm[t] - v;   // exclusive
}

// Phase 3: per-block local scan + bbase offset; emit base[] and dinv[].
__global__ __launch_bounds__(256) void emit_kernel(const int* __restrict__ count,
                                                   const int* __restrict__ bbase,
                                                   int* __restrict__ base,
                                                   float* __restrict__ dinv, int n) {
    int t = threadIdx.x;
    int i0 = blockIdx.x * 1024 + t * 4;
    int v[4];
    int s = 0;
    if (i0 + 4 <= n) {
        int4 q = *(const int4*)&count[i0];
        v[0] = q.x; v[1] = q.y; v[2] = q.z; v[3] = q.w;
        s = v[0] + v[1] + v[2] + v[3];
    } else {
        #pragma unroll
        for (int k = 0; k < 4; k++) {
            int i = i0 + k;
            v[k] = (i < n) ? count[i] : 0;
            s += v[k];
        }
    }
    __shared__ int sm[256];
    sm[t] = s;
    __syncthreads();
    for (int off = 1; off < 256; off <<= 1) {
        int a = (t >= off) ? sm[t - off] : 0;
        __syncthreads();
        sm[t] += a;
        __syncthreads();
    }
    int run = bbase[blockIdx.x] + sm[t] - s;   // exclusive prefix for this thread
    #pragma unroll
    for (int k = 0; k < 4; k++) {
        int i = i0 + k;
        if (i < n) {
            base[i] = run;
            dinv[i] = rsqrtf((float)(v[k] + 1));   // +1 self loop; always > 0
            run += v[k];
        }
    }
}

__global__ void scatter_kernel(const int* __restrict__ rowi, const int* __restrict__ coli,
                               const int* __restrict__ base, int* __restrict__ cursor,
                               int* __restrict__ esrc, int E) {
    int stride = gridDim.x * blockDim.x;
    for (int e = blockIdx.x * blockDim.x + threadIdx.x; e < E; e += stride) {
        int c = coli[e];
        int pos = base[c] + atomicAdd(&cursor[c], 1);
        esrc[pos] = rowi[e];
    }
}

// Y[N][128] = X[N][128] @ W[128][128], fp32. W staged in LDS (64 KiB).
// Block: 256 threads; 8 rows per iteration; thread t -> row t/32, cols 4*(t%32)..+3.
__global__ __launch_bounds__(256) void gemm128_kernel(const float* __restrict__ X,
                                                      const float* __restrict__ W,
                                                      float* __restrict__ Y, int n) {
    __shared__ float Wl[128 * 128];
    int t = threadIdx.x;
    for (int i = t * 4; i < 128 * 128; i += 1024) {
        *(float4*)&Wl[i] = *(const float4*)&W[i];
    }
    __syncthreads();
    int rl = t >> 5;           // 0..7
    int c4 = (t & 31) * 4;     // column base
    for (int r0 = blockIdx.x * 8; r0 < n; r0 += gridDim.x * 8) {
        int r = r0 + rl;
        if (r < n) {
            float4 acc = {0.f, 0.f, 0.f, 0.f};
            const float* xr = &X[(size_t)r * 128];
            for (int k = 0; k < 128; k += 4) {
                float4 xv = *(const float4*)&xr[k];   // broadcast across 32 lanes
                float4 w0 = *(float4*)&Wl[(k + 0) * 128 + c4];
                acc.x += xv.x * w0.x; acc.y += xv.x * w0.y; acc.z += xv.x * w0.z; acc.w += xv.x * w0.w;
                float4 w1 = *(float4*)&Wl[(k + 1) * 128 + c4];
                acc.x += xv.y * w1.x; acc.y += xv.y * w1.y; acc.z += xv.y * w1.z; acc.w += xv.y * w1.w;
                float4 w2 = *(float4*)&Wl[(k + 2) * 128 + c4];
                acc.x += xv.z * w2.x; acc.y += xv.z * w2.y; acc.z += xv.z * w2.z; acc.w += xv.z * w2.w;
                float4 w3 = *(float4*)&Wl[(k + 3) * 128 + c4];
                acc.x += xv.w * w3.x; acc.y += xv.w * w3.y; acc.z += xv.w * w3.z; acc.w += xv.w * w3.w;
            }
            *(float4*)&Y[(size_t)r * 128 + c4] = acc;
        }
    }
}

// One wave per node: out[n][c] = dinv[n]*( sum_src dinv[src]*XW[src][c] + dinv[n]*XW[n][c] )
__global__ void prop_kernel(const float* __restrict__ XW, const int* __restrict__ base,
                            const int* __restrict__ count, const int* __restrict__ esrc,
                            const float* __restrict__ dinv, float* __restrict__ out, int n) {
    int wave = (int)((blockIdx.x * blockDim.x + threadIdx.x) >> 6);
    int lane = threadIdx.x & 63;
    if (wave >= n) return;
    int b = base[wave];
    int cnt = count[wave];
    float din = dinv[wave];
    const float2* xw2 = (const float2*)XW;
    float2 acc = {0.f, 0.f};
    for (int i = 0; i < cnt; i++) {
        int src = esrc[b + i];
        float w = dinv[src];
        float2 v = xw2[(size_t)src * 64 + lane];
        acc.x += w * v.x;
        acc.y += w * v.y;
    }
    float2 vs = xw2[(size_t)wave * 64 + lane];
    acc.x = din * (acc.x + din * vs.x);
    acc.y = din * (acc.y + din * vs.y);
    ((float2*)out)[(size_t)wave * 64 + lane] = acc;
}

// Per-channel sum / sumsq over rows; optional elementwise gate M <- M*H first.
__global__ void stats_kernel(float* __restrict__ M, const float* __restrict__ H,
                             float* __restrict__ sums, float* __restrict__ sumsq,
                             int n, int gate) {
    int t = threadIdx.x;
    int col = t & 127;
    int rhalf = t >> 7;  // 0..1
    float s = 0.f, s2 = 0.f;
    for (int r = blockIdx.x * 2 + rhalf; r < n; r += gridDim.x * 2) {
        size_t idx = (size_t)r * 128 + col;
        float v = M[idx];
        if (gate) { v = v * H[idx]; M[idx] = v; }
        s += v;
        s2 += v * v;
    }
    __shared__ float ls[256], ls2[256];
    ls[t] = s; ls2[t] = s2;
    __syncthreads();
    if (t < 128) {
        s = ls[t] + ls[t + 128];
        s2 = ls2[t] + ls2[t + 128];
        atomicAdd(&sums[col], s);
        atomicAdd(&sumsq[col], s2);
    }
}

__global__ void bnapply_kernel(const float* __restrict__ M, const float* __restrict__ sums,
                               const float* __restrict__ sumsq,
                               const float* __restrict__ g, const float* __restrict__ bet,
                               float* __restrict__ Hout, int n) {
    size_t total = (size_t)n * 128;
    float invn = 1.f / (float)n;
    for (size_t idx = (size_t)blockIdx.x * blockDim.x + threadIdx.x; idx < total;
         idx += (size_t)gridDim.x * blockDim.x) {
        int col = (int)(idx & 127);
        float mu = sums[col] * invn;
        float var = sumsq[col] * invn - mu * mu;
        float a = g[col] * rsqrtf(var + 1e-5f);
        float b = bet[col] - mu * a;
        Hout[idx] = M[idx] * a + b;
    }
}

// result[n] = dot(h[n], ow[0:128]) + dot(BN3(gated[n]), ow[128:256]) + ob
__global__ void final_kernel(const float* __restrict__ H, const float* __restrict__ G,
                             const float* __restrict__ sums3, const float* __restrict__ sumsq3,
                             const float* __restrict__ g3, const float* __restrict__ b3,
                             const float* __restrict__ ow, const float* __restrict__ ob,
                             float* __restrict__ out, int n) {
    int wave = (int)((blockIdx.x * blockDim.x + threadIdx.x) >> 6);
    int lane = threadIdx.x & 63;
    if (wave >= n) return;
    int c0 = 2 * lane, c1 = c0 + 1;
    float invn = 1.f / (float)n;
    float2 h2 = ((const float2*)H)[(size_t)wave * 64 + lane];
    float2 g2 = ((const float2*)G)[(size_t)wave * 64 + lane];
    float mu0 = sums3[c0] * invn;
    float var0 = sumsq3[c0] * invn - mu0 * mu0;
    float a0 = g3[c0] * rsqrtf(var0 + 1e-5f);
    float bb0 = b3[c0] - mu0 * a0;
    float mu1 = sums3[c1] * invn;
    float var1 = sumsq3[c1] * invn - mu1 * mu1;
    float a1 = g3[c1] * rsqrtf(var1 + 1e-5f);
    float bb1 = b3[c1] - mu1 * a1;
    float o0 = g2.x * a0 + bb0;
    float o1 = g2.y * a1 + bb1;
    float partial = h2.x * ow[c0] + h2.y * ow[c1] + o0 * ow[128 + c0] + o1 * ow[128 + c1];
    #pragma unroll
    for (int off = 32; off > 0; off >>= 1) partial += __shfl_down(partial, off);
    if (lane == 0) out[wave] = partial + ob[0];
}

extern "C" void kernel_launch(void* const* d_in, const int* in_sizes, int n_in,
                              void* d_out, int out_size, void* d_ws, size_t ws_size,
                              hipStream_t stream) {
    const float* x     = (const float*)d_in[0];
    const void*  ei    = d_in[1];
    const float* gcn_w = (const float*)d_in[2];
    const float* bn1_g = (const float*)d_in[4];
    const float* bn1_b = (const float*)d_in[5];
    const float* dcn_w = (const float*)d_in[6];
    const float* bn3_g = (const float*)d_in[8];
    const float* bn3_b = (const float*)d_in[9];
    const float* out_w = (const float*)d_in[10];
    const float* out_b = (const float*)d_in[11];
    float* out = (float*)d_out;

    int N = in_sizes[0] / 128;
    int E = in_sizes[1] / 2;
    size_t N128 = (size_t)N * 128;

    float* A     = (float*)d_ws;            // xw / hw           [N*128]
    float* B     = A + N128;                // agg (reused)      [N*128]
    float* H     = B + N128;                // h                 [N*128]
    int*   rowi  = (int*)(H + N128);        // [E]
    int*   coli  = rowi + E;                // [E]
    int*   esrc  = coli + E;                // [E]
    float* dinv  = (float*)(esrc + E);      // [N]
    int*   base  = (int*)(dinv + N);        // [N]
    int*   bsum  = base + N;                // [1024]
    // ---- zeroed region starts here ----
    int*   count  = bsum + 1024;            // [N]
    int*   cursor = count + N;              // [N]
    float* sums1  = (float*)(cursor + N);   // [128]
    float* sumsq1 = sums1 + 128;            // [128]
    float* sums3  = sumsq1 + 128;           // [128]
    float* sumsq3 = sums3 + 128;            // [128]
    int*   flag   = (int*)(sumsq3 + 128);   // [1]

    size_t zero_bytes = (size_t)((char*)(flag + 1) - (char*)count);
    hipMemsetAsync(count, 0, zero_bytes, stream);

    int egrid = (E + 255) / 256;
    if (egrid > 2048) egrid = 2048;
    int pgrid = (N + 3) / 4;     // 4 waves / block, one node per wave
    int nb = (N + 1023) / 1024;  // scan blocks (<=1024 for N<=1M)

    detect_kernel<<<1, 1024, 0, stream>>>((const int*)ei, flag);
    convert_kernel<<<egrid, 256, 0, stream>>>(ei, E, flag, rowi, coli, count);
    bsum_kernel<<<nb, 256, 0, stream>>>(count, bsum, N);
    scanb_kernel<<<1, 1024, 0, stream>>>(bsum, nb);
    emit_kernel<<<nb, 256, 0, stream>>>(count, bsum, base, dinv, N);
    scatter_kernel<<<egrid, 256, 0, stream>>>(rowi, coli, base, cursor, esrc, E);

    gemm128_kernel<<<512, 256, 0, stream>>>(x, gcn_w, A, N);
    prop_kernel<<<pgrid, 256, 0, stream>>>(A, base, count, esrc, dinv, B, N);
    stats_kernel<<<1024, 256, 0, stream>>>(B, nullptr, sums1, sumsq1, N, 0);

    int agrid = (int)((N128 + 255) / 256);
    if (agrid > 4096) agrid = 4096;
    bnapply_kernel<<<agrid, 256, 0, stream>>>(B, sums1, sumsq1, bn1_g, bn1_b, H, N);

    gemm128_kernel<<<512, 256, 0, stream>>>(H, dcn_w, A, N);
    prop_kernel<<<pgrid, 256, 0, stream>>>(A, base, count, esrc, dinv, B, N);
    stats_kernel<<<1024, 256, 0, stream>>>(B, H, sums3, sumsq3, N, 1);

    final_kernel<<<pgrid, 256, 0, stream>>>(H, B, sums3, sumsq3, bn3_g, bn3_b,
                                            out_w, out_b, out, N);
}

// Round 5
// 317.240 us; speedup vs baseline: 1.5347x; 1.2298x over previous
//
#include <hip/hip_runtime.h>
#include <hip/hip_bf16.h>
#include <cstdint>

// ---------------------------------------------------------------------------
// DGNN pipeline, CSR-based aggregation (no scatter atomics on features).
// Biases gcn_b / dcn_b cancel inside the following batchnorms and are skipped.
// R1: chunk-per-thread single-block scan -> REGRESSED (93->110us).
// R2: 3-kernel multi-block scan -> scan path off the profile; 390us total.
// R3: prop gather feed converted to bf16 + 4x edge unroll. fp32 accumulate.
// R4: fix compile (manual RNE fp32->bf16; no .data member on __hip_bfloat16).
// ---------------------------------------------------------------------------

__device__ __forceinline__ ushort f2bf(float f) {
    union { float f; unsigned u; } c; c.f = f;
    unsigned u = c.u;
    return (ushort)((u + 0x7fffu + ((u >> 16) & 1u)) >> 16);   // RNE
}

// Detect whether edge_index arrived as int64 (high int32 words all zero for
// values < 2^31) or int32 (odd int32 positions are random node ids).
__global__ void detect_kernel(const int* __restrict__ ei32, int* __restrict__ flag) {
    int t = threadIdx.x;
    int v = ei32[2 * t + 1];
    if (v != 0) atomicOr(flag, 1);   // nonzero high-word sample => int32 layout
}

__global__ void convert_kernel(const void* __restrict__ ei, int E,
                               const int* __restrict__ flag,
                               int* __restrict__ rowi, int* __restrict__ coli,
                               int* __restrict__ count) {
    int f = *flag;
    int stride = gridDim.x * blockDim.x;
    for (int e = blockIdx.x * blockDim.x + threadIdx.x; e < E; e += stride) {
        int r, c;
        if (f) {
            r = ((const int*)ei)[e];
            c = ((const int*)ei)[E + e];
        } else {
            r = (int)((const long long*)ei)[e];
            c = (int)((const long long*)ei)[E + e];
        }
        rowi[e] = r;
        coli[e] = c;
        atomicAdd(&count[c], 1);
    }
}

// ---- 3-phase multi-block exclusive scan over count[N] ----
__global__ __launch_bounds__(256) void bsum_kernel(const int* __restrict__ count,
                                                   int* __restrict__ bsum, int n) {
    int t = threadIdx.x;
    int i0 = blockIdx.x * 1024 + t * 4;
    int s = 0;
    if (i0 + 4 <= n) {
        int4 v = *(const int4*)&count[i0];
        s = v.x + v.y + v.z + v.w;
    } else {
        for (int i = i0; i < n; i++) s += count[i];
    }
    __shared__ int ls[256];
    ls[t] = s;
    __syncthreads();
    for (int off = 128; off > 0; off >>= 1) {
        if (t < off) ls[t] += ls[t + off];
        __syncthreads();
    }
    if (t == 0) bsum[blockIdx.x] = ls[0];
}

__global__ void scanb_kernel(int* __restrict__ bsum, int nb) {
    __shared__ int sm[1024];
    int t = threadIdx.x;
    int v = (t < nb) ? bsum[t] : 0;
    sm[t] = v;
    __syncthreads();
    for (int off = 1; off < 1024; off <<= 1) {
        int a = (t >= off) ? sm[t - off] : 0;
        __syncthreads();
        sm[t] += a;
        __syncthreads();
    }
    if (t < nb) bsum[t] = sm[t] - v;   // exclusive
}

__global__ __launch_bounds__(256) void emit_kernel(const int* __restrict__ count,
                                                   const int* __restrict__ bbase,
                                                   int* __restrict__ base,
                                                   float* __restrict__ dinv, int n) {
    int t = threadIdx.x;
    int i0 = blockIdx.x * 1024 + t * 4;
    int v[4];
    int s = 0;
    if (i0 + 4 <= n) {
        int4 q = *(const int4*)&count[i0];
        v[0] = q.x; v[1] = q.y; v[2] = q.z; v[3] = q.w;
        s = v[0] + v[1] + v[2] + v[3];
    } else {
        #pragma unroll
        for (int k = 0; k < 4; k++) {
            int i = i0 + k;
            v[k] = (i < n) ? count[i] : 0;
            s += v[k];
        }
    }
    __shared__ int sm[256];
    sm[t] = s;
    __syncthreads();
    for (int off = 1; off < 256; off <<= 1) {
        int a = (t >= off) ? sm[t - off] : 0;
        __syncthreads();
        sm[t] += a;
        __syncthreads();
    }
    int run = bbase[blockIdx.x] + sm[t] - s;
    #pragma unroll
    for (int k = 0; k < 4; k++) {
        int i = i0 + k;
        if (i < n) {
            base[i] = run;
            dinv[i] = rsqrtf((float)(v[k] + 1));   // +1 self loop; always > 0
            run += v[k];
        }
    }
}

__global__ void scatter_kernel(const int* __restrict__ rowi, const int* __restrict__ coli,
                               const int* __restrict__ base, int* __restrict__ cursor,
                               int* __restrict__ esrc, int E) {
    int stride = gridDim.x * blockDim.x;
    for (int e = blockIdx.x * blockDim.x + threadIdx.x; e < E; e += stride) {
        int c = coli[e];
        int pos = base[c] + atomicAdd(&cursor[c], 1);
        esrc[pos] = rowi[e];
    }
}

// Y[N][128] = X[N][128] @ W[128][128]; output packed bf16 (RNE).
// W staged in LDS. 256 threads; thread t -> row t/32, cols 4*(t%32)..+3.
__global__ __launch_bounds__(256) void gemm128_kernel(const float* __restrict__ X,
                                                      const float* __restrict__ W,
                                                      ushort* __restrict__ Ybf, int n) {
    __shared__ float Wl[128 * 128];
    int t = threadIdx.x;
    for (int i = t * 4; i < 128 * 128; i += 1024) {
        *(float4*)&Wl[i] = *(const float4*)&W[i];
    }
    __syncthreads();
    int rl = t >> 5;           // 0..7
    int c4 = (t & 31) * 4;     // column base
    for (int r0 = blockIdx.x * 8; r0 < n; r0 += gridDim.x * 8) {
        int r = r0 + rl;
        if (r < n) {
            float4 acc = {0.f, 0.f, 0.f, 0.f};
            const float* xr = &X[(size_t)r * 128];
            for (int k = 0; k < 128; k += 4) {
                float4 xv = *(const float4*)&xr[k];   // broadcast across 32 lanes
                float4 w0 = *(float4*)&Wl[(k + 0) * 128 + c4];
                acc.x += xv.x * w0.x; acc.y += xv.x * w0.y; acc.z += xv.x * w0.z; acc.w += xv.x * w0.w;
                float4 w1 = *(float4*)&Wl[(k + 1) * 128 + c4];
                acc.x += xv.y * w1.x; acc.y += xv.y * w1.y; acc.z += xv.y * w1.z; acc.w += xv.y * w1.w;
                float4 w2 = *(float4*)&Wl[(k + 2) * 128 + c4];
                acc.x += xv.z * w2.x; acc.y += xv.z * w2.y; acc.z += xv.z * w2.z; acc.w += xv.z * w2.w;
                float4 w3 = *(float4*)&Wl[(k + 3) * 128 + c4];
                acc.x += xv.w * w3.x; acc.y += xv.w * w3.y; acc.z += xv.w * w3.z; acc.w += xv.w * w3.w;
            }
            ushort4 o;
            o.x = f2bf(acc.x);
            o.y = f2bf(acc.y);
            o.z = f2bf(acc.z);
            o.w = f2bf(acc.w);
            *(ushort4*)&Ybf[(size_t)r * 128 + c4] = o;
        }
    }
}

__device__ __forceinline__ float bflo(unsigned u) {
    union { unsigned i; float f; } c; c.i = u << 16; return c.f;
}
__device__ __forceinline__ float bfhi(unsigned u) {
    union { unsigned i; float f; } c; c.i = u & 0xffff0000u; return c.f;
}

// One wave per node: out[n][c] = dinv[n]*( sum_src dinv[src]*XW[src][c] + dinv[n]*XW[n][c] )
// XW is packed bf16 (2 channels per u32 per lane). fp32 accumulate. 4x unroll.
__global__ void prop_kernel(const unsigned* __restrict__ XWb, const int* __restrict__ base,
                            const int* __restrict__ count, const int* __restrict__ esrc,
                            const float* __restrict__ dinv, float* __restrict__ out, int n) {
    int wave = (int)((blockIdx.x * blockDim.x + threadIdx.x) >> 6);
    int lane = threadIdx.x & 63;
    if (wave >= n) return;
    int b = base[wave];
    int cnt = count[wave];
    float din = dinv[wave];
    float accx = 0.f, accy = 0.f;
    int i = 0;
    for (; i + 4 <= cnt; i += 4) {
        int s0 = esrc[b + i];
        int s1 = esrc[b + i + 1];
        int s2 = esrc[b + i + 2];
        int s3 = esrc[b + i + 3];
        float w0 = dinv[s0], w1 = dinv[s1], w2 = dinv[s2], w3 = dinv[s3];
        unsigned v0 = XWb[(size_t)s0 * 64 + lane];
        unsigned v1 = XWb[(size_t)s1 * 64 + lane];
        unsigned v2 = XWb[(size_t)s2 * 64 + lane];
        unsigned v3 = XWb[(size_t)s3 * 64 + lane];
        accx += w0 * bflo(v0); accy += w0 * bfhi(v0);
        accx += w1 * bflo(v1); accy += w1 * bfhi(v1);
        accx += w2 * bflo(v2); accy += w2 * bfhi(v2);
        accx += w3 * bflo(v3); accy += w3 * bfhi(v3);
    }
    for (; i < cnt; i++) {
        int s = esrc[b + i];
        float w = dinv[s];
        unsigned v = XWb[(size_t)s * 64 + lane];
        accx += w * bflo(v);
        accy += w * bfhi(v);
    }
    unsigned vs = XWb[(size_t)wave * 64 + lane];
    accx = din * (accx + din * bflo(vs));
    accy = din * (accy + din * bfhi(vs));
    float2 o; o.x = accx; o.y = accy;
    ((float2*)out)[(size_t)wave * 64 + lane] = o;
}

// Per-channel sum / sumsq over rows; optional elementwise gate M <- M*H first.
__global__ void stats_kernel(float* __restrict__ M, const float* __restrict__ H,
                             float* __restrict__ sums, float* __restrict__ sumsq,
                             int n, int gate) {
    int t = threadIdx.x;
    int col = t & 127;
    int rhalf = t >> 7;  // 0..1
    float s = 0.f, s2 = 0.f;
    for (int r = blockIdx.x * 2 + rhalf; r < n; r += gridDim.x * 2) {
        size_t idx = (size_t)r * 128 + col;
        float v = M[idx];
        if (gate) { v = v * H[idx]; M[idx] = v; }
        s += v;
        s2 += v * v;
    }
    __shared__ float ls[256], ls2[256];
    ls[t] = s; ls2[t] = s2;
    __syncthreads();
    if (t < 128) {
        s = ls[t] + ls[t + 128];
        s2 = ls2[t] + ls2[t + 128];
        atomicAdd(&sums[col], s);
        atomicAdd(&sumsq[col], s2);
    }
}

__global__ void bnapply_kernel(const float* __restrict__ M, const float* __restrict__ sums,
                               const float* __restrict__ sumsq,
                               const float* __restrict__ g, const float* __restrict__ bet,
                               float* __restrict__ Hout, int n) {
    size_t total = (size_t)n * 128;
    float invn = 1.f / (float)n;
    for (size_t idx = (size_t)blockIdx.x * blockDim.x + threadIdx.x; idx < total;
         idx += (size_t)gridDim.x * blockDim.x) {
        int col = (int)(idx & 127);
        float mu = sums[col] * invn;
        float var = sumsq[col] * invn - mu * mu;
        float a = g[col] * rsqrtf(var + 1e-5f);
        float b = bet[col] - mu * a;
        Hout[idx] = M[idx] * a + b;
    }
}

// result[n] = dot(h[n], ow[0:128]) + dot(BN3(gated[n]), ow[128:256]) + ob
__global__ void final_kernel(const float* __restrict__ H, const float* __restrict__ G,
                             const float* __restrict__ sums3, const float* __restrict__ sumsq3,
                             const float* __restrict__ g3, const float* __restrict__ b3,
                             const float* __restrict__ ow, const float* __restrict__ ob,
                             float* __restrict__ out, int n) {
    int wave = (int)((blockIdx.x * blockDim.x + threadIdx.x) >> 6);
    int lane = threadIdx.x & 63;
    if (wave >= n) return;
    int c0 = 2 * lane, c1 = c0 + 1;
    float invn = 1.f / (float)n;
    float2 h2 = ((const float2*)H)[(size_t)wave * 64 + lane];
    float2 g2 = ((const float2*)G)[(size_t)wave * 64 + lane];
    float mu0 = sums3[c0] * invn;
    float var0 = sumsq3[c0] * invn - mu0 * mu0;
    float a0 = g3[c0] * rsqrtf(var0 + 1e-5f);
    float bb0 = b3[c0] - mu0 * a0;
    float mu1 = sums3[c1] * invn;
    float var1 = sumsq3[c1] * invn - mu1 * mu1;
    float a1 = g3[c1] * rsqrtf(var1 + 1e-5f);
    float bb1 = b3[c1] - mu1 * a1;
    float o0 = g2.x * a0 + bb0;
    float o1 = g2.y * a1 + bb1;
    float partial = h2.x * ow[c0] + h2.y * ow[c1] + o0 * ow[128 + c0] + o1 * ow[128 + c1];
    #pragma unroll
    for (int off = 32; off > 0; off >>= 1) partial += __shfl_down(partial, off);
    if (lane == 0) out[wave] = partial + ob[0];
}

extern "C" void kernel_launch(void* const* d_in, const int* in_sizes, int n_in,
                              void* d_out, int out_size, void* d_ws, size_t ws_size,
                              hipStream_t stream) {
    const float* x     = (const float*)d_in[0];
    const void*  ei    = d_in[1];
    const float* gcn_w = (const float*)d_in[2];
    const float* bn1_g = (const float*)d_in[4];
    const float* bn1_b = (const float*)d_in[5];
    const float* dcn_w = (const float*)d_in[6];
    const float* bn3_g = (const float*)d_in[8];
    const float* bn3_b = (const float*)d_in[9];
    const float* out_w = (const float*)d_in[10];
    const float* out_b = (const float*)d_in[11];
    float* out = (float*)d_out;

    int N = in_sizes[0] / 128;
    int E = in_sizes[1] / 2;
    size_t N128 = (size_t)N * 128;

    float* A     = (float*)d_ws;            // bf16 xw/hw (packed) [N*128 floats reserved]
    float* B     = A + N128;                // agg (reused)      [N*128]
    float* H     = B + N128;                // h                 [N*128]
    int*   rowi  = (int*)(H + N128);        // [E]
    int*   coli  = rowi + E;                // [E]
    int*   esrc  = coli + E;                // [E]
    float* dinv  = (float*)(esrc + E);      // [N]
    int*   base  = (int*)(dinv + N);        // [N]
    int*   bsum  = base + N;                // [1024]
    // ---- zeroed region starts here ----
    int*   count  = bsum + 1024;            // [N]
    int*   cursor = count + N;              // [N]
    float* sums1  = (float*)(cursor + N);   // [128]
    float* sumsq1 = sums1 + 128;            // [128]
    float* sums3  = sumsq1 + 128;           // [128]
    float* sumsq3 = sums3 + 128;            // [128]
    int*   flag   = (int*)(sumsq3 + 128);   // [1]

    size_t zero_bytes = (size_t)((char*)(flag + 1) - (char*)count);
    (void)hipMemsetAsync(count, 0, zero_bytes, stream);

    int egrid = (E + 255) / 256;
    if (egrid > 2048) egrid = 2048;
    int pgrid = (N + 3) / 4;     // 4 waves / block, one node per wave
    int nb = (N + 1023) / 1024;  // scan blocks

    detect_kernel<<<1, 1024, 0, stream>>>((const int*)ei, flag);
    convert_kernel<<<egrid, 256, 0, stream>>>(ei, E, flag, rowi, coli, count);
    bsum_kernel<<<nb, 256, 0, stream>>>(count, bsum, N);
    scanb_kernel<<<1, 1024, 0, stream>>>(bsum, nb);
    emit_kernel<<<nb, 256, 0, stream>>>(count, bsum, base, dinv, N);
    scatter_kernel<<<egrid, 256, 0, stream>>>(rowi, coli, base, cursor, esrc, E);

    ushort* Abf = (ushort*)A;

    gemm128_kernel<<<512, 256, 0, stream>>>(x, gcn_w, Abf, N);
    prop_kernel<<<pgrid, 256, 0, stream>>>((const unsigned*)Abf, base, count, esrc, dinv, B, N);
    stats_kernel<<<1024, 256, 0, stream>>>(B, nullptr, sums1, sumsq1, N, 0);

    int agrid = (int)((N128 + 255) / 256);
    if (agrid > 4096) agrid = 4096;
    bnapply_kernel<<<agrid, 256, 0, stream>>>(B, sums1, sumsq1, bn1_g, bn1_b, H, N);

    gemm128_kernel<<<512, 256, 0, stream>>>(H, dcn_w, Abf, N);
    prop_kernel<<<pgrid, 256, 0, stream>>>((const unsigned*)Abf, base, count, esrc, dinv, B, N);
    stats_kernel<<<1024, 256, 0, stream>>>(B, H, sums3, sumsq3, N, 1);

    final_kernel<<<pgrid, 256, 0, stream>>>(H, B, sums3, sumsq3, bn3_g, bn3_b,
                                            out_w, out_b, out, N);
}

// Round 6
// 272.486 us; speedup vs baseline: 1.7868x; 1.1642x over previous
//
#include <hip/hip_runtime.h>
#include <hip/hip_bf16.h>
#include <cstdint>

// ---------------------------------------------------------------------------
// DGNN pipeline, CSR-based aggregation (no scatter atomics on features).
// Biases gcn_b / dcn_b cancel inside the following batchnorms and are skipped.
// R2: multi-block scan. R3/R4: bf16 gather feed for prop (+4x unroll).
// R5: GEMM moved to MFMA bf16 (was fp32 VALU at 26% VALUBusy, 48us each):
//     WT pre-transposed to bf16, LDS pad-stride 136, mfma_f32_16x16x32_bf16,
//     A loaded fp32->bf16 in-register. Scatter now emits (src,dinv) int2 to
//     kill prop's dependent dinv gather.
// ---------------------------------------------------------------------------

typedef __attribute__((ext_vector_type(8))) short bf16x8;
typedef __attribute__((ext_vector_type(4))) float f32x4;

__device__ __forceinline__ ushort f2bf(float f) {
    union { float f; unsigned u; } c; c.f = f;
    unsigned u = c.u;
    return (ushort)((u + 0x7fffu + ((u >> 16) & 1u)) >> 16);   // RNE
}

// Detect whether edge_index arrived as int64 (high int32 words all zero for
// values < 2^31) or int32 (odd int32 positions are random node ids).
__global__ void detect_kernel(const int* __restrict__ ei32, int* __restrict__ flag) {
    int t = threadIdx.x;
    int v = ei32[2 * t + 1];
    if (v != 0) atomicOr(flag, 1);   // nonzero high-word sample => int32 layout
}

__global__ void convert_kernel(const void* __restrict__ ei, int E,
                               const int* __restrict__ flag,
                               int* __restrict__ rowi, int* __restrict__ coli,
                               int* __restrict__ count) {
    int f = *flag;
    int stride = gridDim.x * blockDim.x;
    for (int e = blockIdx.x * blockDim.x + threadIdx.x; e < E; e += stride) {
        int r, c;
        if (f) {
            r = ((const int*)ei)[e];
            c = ((const int*)ei)[E + e];
        } else {
            r = (int)((const long long*)ei)[e];
            c = (int)((const long long*)ei)[E + e];
        }
        rowi[e] = r;
        coli[e] = c;
        atomicAdd(&count[c], 1);
    }
}

// ---- 3-phase multi-block exclusive scan over count[N] ----
__global__ __launch_bounds__(256) void bsum_kernel(const int* __restrict__ count,
                                                   int* __restrict__ bsum, int n) {
    int t = threadIdx.x;
    int i0 = blockIdx.x * 1024 + t * 4;
    int s = 0;
    if (i0 + 4 <= n) {
        int4 v = *(const int4*)&count[i0];
        s = v.x + v.y + v.z + v.w;
    } else {
        for (int i = i0; i < n; i++) s += count[i];
    }
    __shared__ int ls[256];
    ls[t] = s;
    __syncthreads();
    for (int off = 128; off > 0; off >>= 1) {
        if (t < off) ls[t] += ls[t + off];
        __syncthreads();
    }
    if (t == 0) bsum[blockIdx.x] = ls[0];
}

__global__ void scanb_kernel(int* __restrict__ bsum, int nb) {
    __shared__ int sm[1024];
    int t = threadIdx.x;
    int v = (t < nb) ? bsum[t] : 0;
    sm[t] = v;
    __syncthreads();
    for (int off = 1; off < 1024; off <<= 1) {
        int a = (t >= off) ? sm[t - off] : 0;
        __syncthreads();
        sm[t] += a;
        __syncthreads();
    }
    if (t < nb) bsum[t] = sm[t] - v;   // exclusive
}

__global__ __launch_bounds__(256) void emit_kernel(const int* __restrict__ count,
                                                   const int* __restrict__ bbase,
                                                   int* __restrict__ base,
                                                   float* __restrict__ dinv, int n) {
    int t = threadIdx.x;
    int i0 = blockIdx.x * 1024 + t * 4;
    int v[4];
    int s = 0;
    if (i0 + 4 <= n) {
        int4 q = *(const int4*)&count[i0];
        v[0] = q.x; v[1] = q.y; v[2] = q.z; v[3] = q.w;
        s = v[0] + v[1] + v[2] + v[3];
    } else {
        #pragma unroll
        for (int k = 0; k < 4; k++) {
            int i = i0 + k;
            v[k] = (i < n) ? count[i] : 0;
            s += v[k];
        }
    }
    __shared__ int sm[256];
    sm[t] = s;
    __syncthreads();
    for (int off = 1; off < 256; off <<= 1) {
        int a = (t >= off) ? sm[t - off] : 0;
        __syncthreads();
        sm[t] += a;
        __syncthreads();
    }
    int run = bbase[blockIdx.x] + sm[t] - s;
    #pragma unroll
    for (int k = 0; k < 4; k++) {
        int i = i0 + k;
        if (i < n) {
            base[i] = run;
            dinv[i] = rsqrtf((float)(v[k] + 1));   // +1 self loop; always > 0
            run += v[k];
        }
    }
}

// Emit (src, dinv[src]) pairs per destination bucket.
__global__ void scatter_kernel(const int* __restrict__ rowi, const int* __restrict__ coli,
                               const int* __restrict__ base, int* __restrict__ cursor,
                               const float* __restrict__ dinv,
                               int2* __restrict__ esrc2, int E) {
    int stride = gridDim.x * blockDim.x;
    for (int e = blockIdx.x * blockDim.x + threadIdx.x; e < E; e += stride) {
        int c = coli[e];
        int r = rowi[e];
        int pos = base[c] + atomicAdd(&cursor[c], 1);
        int2 v;
        v.x = r;
        v.y = __float_as_int(dinv[r]);
        esrc2[pos] = v;
    }
}

// WT[c*128 + k] = bf16(W[k*128 + c]); 16384 elements, one thread each.
__global__ void wtrans_kernel(const float* __restrict__ W, ushort* __restrict__ WT) {
    int t = blockIdx.x * 256 + threadIdx.x;
    if (t < 128 * 128) {
        int c = t >> 7, k = t & 127;
        WT[t] = f2bf(W[k * 128 + c]);
    }
}

// Y[N][128] = bf16(X) @ bf16(W) via MFMA, output packed bf16.
// Block: 4 waves x 16 rows = 64 rows. WT staged in LDS, pad stride 136
// (b128 reads then hit the optimal 8-lanes-per-128B-window distribution).
// A/B fragments staged with mirrored (l&15, k=(l>>4)*8+i) conventions:
// any intra-fragment k-interleave cancels since A and B agree.
// C/D mapping (HW-verified): col = lane&15, row = (lane>>4)*4 + reg.
__global__ __launch_bounds__(256) void gemm_mfma_kernel(const float* __restrict__ X,
                                                        const ushort* __restrict__ WT,
                                                        ushort* __restrict__ Ybf, int n) {
    __shared__ ushort Wl[128 * 136];
    int t = threadIdx.x;
    // stage WT (bf16, [c][k]) -> LDS with row stride 136
    for (int idx = t * 8; idx < 128 * 128; idx += 256 * 8) {
        int c = idx >> 7;
        int k = idx & 127;
        *(uint4*)&Wl[c * 136 + k] = *(const uint4*)&WT[idx];
    }
    __syncthreads();

    int wid = t >> 6;
    int lane = t & 63;
    int m0 = blockIdx.x * 64 + wid * 16;
    if (m0 >= n) return;                      // after the only barrier: safe
    int row = m0 + (lane & 15);
    int rc = row < n ? row : n - 1;           // clamp loads; stores predicated
    const float* xr = &X[(size_t)rc * 128];
    int kg = (lane >> 4) * 8;                 // k sub-offset: 0,8,16,24

    f32x4 acc[8];
    #pragma unroll
    for (int i = 0; i < 8; i++) acc[i] = (f32x4){0.f, 0.f, 0.f, 0.f};

    #pragma unroll
    for (int ks = 0; ks < 4; ks++) {
        int k0 = ks * 32 + kg;
        float4 lo = *(const float4*)&xr[k0];
        float4 hi = *(const float4*)&xr[k0 + 4];
        bf16x8 a;
        a[0] = (short)f2bf(lo.x); a[1] = (short)f2bf(lo.y);
        a[2] = (short)f2bf(lo.z); a[3] = (short)f2bf(lo.w);
        a[4] = (short)f2bf(hi.x); a[5] = (short)f2bf(hi.y);
        a[6] = (short)f2bf(hi.z); a[7] = (short)f2bf(hi.w);
        #pragma unroll
        for (int nt = 0; nt < 8; nt++) {
            int c = nt * 16 + (lane & 15);
            bf16x8 b = *(bf16x8*)&Wl[c * 136 + k0];
            acc[nt] = __builtin_amdgcn_mfma_f32_16x16x32_bf16(a, b, acc[nt], 0, 0, 0);
        }
    }

    int ro = m0 + (lane >> 4) * 4;
    int co = lane & 15;
    #pragma unroll
    for (int nt = 0; nt < 8; nt++) {
        #pragma unroll
        for (int i = 0; i < 4; i++) {
            int r = ro + i;
            if (r < n) Ybf[(size_t)r * 128 + nt * 16 + co] = f2bf(acc[nt][i]);
        }
    }
}

__device__ __forceinline__ float bflo(unsigned u) {
    union { unsigned i; float f; } c; c.i = u << 16; return c.f;
}
__device__ __forceinline__ float bfhi(unsigned u) {
    union { unsigned i; float f; } c; c.i = u & 0xffff0000u; return c.f;
}

// One wave per node: out[n][c] = dinv[n]*( sum_src dinv[src]*XW[src][c] + dinv[n]*XW[n][c] )
// XW packed bf16 (2 ch per u32 per lane); (src,w) pairs 8B; fp32 accum; 4x unroll.
__global__ void prop_kernel(const unsigned* __restrict__ XWb, const int* __restrict__ base,
                            const int* __restrict__ count, const int2* __restrict__ esrc2,
                            const float* __restrict__ dinv, float* __restrict__ out, int n) {
    int wave = (int)((blockIdx.x * blockDim.x + threadIdx.x) >> 6);
    int lane = threadIdx.x & 63;
    if (wave >= n) return;
    int b = base[wave];
    int cnt = count[wave];
    float din = dinv[wave];
    float accx = 0.f, accy = 0.f;
    int i = 0;
    for (; i + 4 <= cnt; i += 4) {
        int2 p0 = esrc2[b + i];
        int2 p1 = esrc2[b + i + 1];
        int2 p2 = esrc2[b + i + 2];
        int2 p3 = esrc2[b + i + 3];
        unsigned v0 = XWb[(size_t)p0.x * 64 + lane];
        unsigned v1 = XWb[(size_t)p1.x * 64 + lane];
        unsigned v2 = XWb[(size_t)p2.x * 64 + lane];
        unsigned v3 = XWb[(size_t)p3.x * 64 + lane];
        float w0 = __int_as_float(p0.y), w1 = __int_as_float(p1.y);
        float w2 = __int_as_float(p2.y), w3 = __int_as_float(p3.y);
        accx += w0 * bflo(v0); accy += w0 * bfhi(v0);
        accx += w1 * bflo(v1); accy += w1 * bfhi(v1);
        accx += w2 * bflo(v2); accy += w2 * bfhi(v2);
        accx += w3 * bflo(v3); accy += w3 * bfhi(v3);
    }
    for (; i < cnt; i++) {
        int2 p = esrc2[b + i];
        float w = __int_as_float(p.y);
        unsigned v = XWb[(size_t)p.x * 64 + lane];
        accx += w * bflo(v);
        accy += w * bfhi(v);
    }
    unsigned vs = XWb[(size_t)wave * 64 + lane];
    accx = din * (accx + din * bflo(vs));
    accy = din * (accy + din * bfhi(vs));
    float2 o; o.x = accx; o.y = accy;
    ((float2*)out)[(size_t)wave * 64 + lane] = o;
}

// Per-channel sum / sumsq over rows; optional elementwise gate M <- M*H first.
__global__ void stats_kernel(float* __restrict__ M, const float* __restrict__ H,
                             float* __restrict__ sums, float* __restrict__ sumsq,
                             int n, int gate) {
    int t = threadIdx.x;
    int col = t & 127;
    int rhalf = t >> 7;  // 0..1
    float s = 0.f, s2 = 0.f;
    for (int r = blockIdx.x * 2 + rhalf; r < n; r += gridDim.x * 2) {
        size_t idx = (size_t)r * 128 + col;
        float v = M[idx];
        if (gate) { v = v * H[idx]; M[idx] = v; }
        s += v;
        s2 += v * v;
    }
    __shared__ float ls[256], ls2[256];
    ls[t] = s; ls2[t] = s2;
    __syncthreads();
    if (t < 128) {
        s = ls[t] + ls[t + 128];
        s2 = ls2[t] + ls2[t + 128];
        atomicAdd(&sums[col], s);
        atomicAdd(&sumsq[col], s2);
    }
}

__global__ void bnapply_kernel(const float* __restrict__ M, const float* __restrict__ sums,
                               const float* __restrict__ sumsq,
                               const float* __restrict__ g, const float* __restrict__ bet,
                               float* __restrict__ Hout, int n) {
    size_t total = (size_t)n * 128;
    float invn = 1.f / (float)n;
    for (size_t idx = (size_t)blockIdx.x * blockDim.x + threadIdx.x; idx < total;
         idx += (size_t)gridDim.x * blockDim.x) {
        int col = (int)(idx & 127);
        float mu = sums[col] * invn;
        float var = sumsq[col] * invn - mu * mu;
        float a = g[col] * rsqrtf(var + 1e-5f);
        float b = bet[col] - mu * a;
        Hout[idx] = M[idx] * a + b;
    }
}

// result[n] = dot(h[n], ow[0:128]) + dot(BN3(gated[n]), ow[128:256]) + ob
__global__ void final_kernel(const float* __restrict__ H, const float* __restrict__ G,
                             const float* __restrict__ sums3, const float* __restrict__ sumsq3,
                             const float* __restrict__ g3, const float* __restrict__ b3,
                             const float* __restrict__ ow, const float* __restrict__ ob,
                             float* __restrict__ out, int n) {
    int wave = (int)((blockIdx.x * blockDim.x + threadIdx.x) >> 6);
    int lane = threadIdx.x & 63;
    if (wave >= n) return;
    int c0 = 2 * lane, c1 = c0 + 1;
    float invn = 1.f / (float)n;
    float2 h2 = ((const float2*)H)[(size_t)wave * 64 + lane];
    float2 g2 = ((const float2*)G)[(size_t)wave * 64 + lane];
    float mu0 = sums3[c0] * invn;
    float var0 = sumsq3[c0] * invn - mu0 * mu0;
    float a0 = g3[c0] * rsqrtf(var0 + 1e-5f);
    float bb0 = b3[c0] - mu0 * a0;
    float mu1 = sums3[c1] * invn;
    float var1 = sumsq3[c1] * invn - mu1 * mu1;
    float a1 = g3[c1] * rsqrtf(var1 + 1e-5f);
    float bb1 = b3[c1] - mu1 * a1;
    float o0 = g2.x * a0 + bb0;
    float o1 = g2.y * a1 + bb1;
    float partial = h2.x * ow[c0] + h2.y * ow[c1] + o0 * ow[128 + c0] + o1 * ow[128 + c1];
    #pragma unroll
    for (int off = 32; off > 0; off >>= 1) partial += __shfl_down(partial, off);
    if (lane == 0) out[wave] = partial + ob[0];
}

extern "C" void kernel_launch(void* const* d_in, const int* in_sizes, int n_in,
                              void* d_out, int out_size, void* d_ws, size_t ws_size,
                              hipStream_t stream) {
    const float* x     = (const float*)d_in[0];
    const void*  ei    = d_in[1];
    const float* gcn_w = (const float*)d_in[2];
    const float* bn1_g = (const float*)d_in[4];
    const float* bn1_b = (const float*)d_in[5];
    const float* dcn_w = (const float*)d_in[6];
    const float* bn3_g = (const float*)d_in[8];
    const float* bn3_b = (const float*)d_in[9];
    const float* out_w = (const float*)d_in[10];
    const float* out_b = (const float*)d_in[11];
    float* out = (float*)d_out;

    int N = in_sizes[0] / 128;
    int E = in_sizes[1] / 2;
    size_t N128 = (size_t)N * 128;

    float* A     = (float*)d_ws;            // bf16 xw/hw (packed) [N*128 floats reserved]
    float* B     = A + N128;                // agg (reused)      [N*128]
    float* H     = B + N128;                // h                 [N*128]
    int*   rowi  = (int*)(H + N128);        // [E]
    int*   coli  = rowi + E;                // [E]
    int2*  esrc2 = (int2*)(coli + E);       // [E] (src, dinv[src])
    float* dinv  = (float*)(esrc2 + E);     // [N]
    int*   base  = (int*)(dinv + N);        // [N]
    int*   bsum  = base + N;                // [1024]
    ushort* WT1  = (ushort*)(bsum + 1024);  // [16384] bf16 gcn_w^T
    ushort* WT2  = WT1 + 16384;             // [16384] bf16 dcn_w^T
    // ---- zeroed region starts here ----
    int*   count  = (int*)(WT2 + 16384);    // [N]
    int*   cursor = count + N;              // [N]
    float* sums1  = (float*)(cursor + N);   // [128]
    float* sumsq1 = sums1 + 128;            // [128]
    float* sums3  = sumsq1 + 128;           // [128]
    float* sumsq3 = sums3 + 128;            // [128]
    int*   flag   = (int*)(sumsq3 + 128);   // [1]

    size_t zero_bytes = (size_t)((char*)(flag + 1) - (char*)count);
    (void)hipMemsetAsync(count, 0, zero_bytes, stream);

    int egrid = (E + 255) / 256;
    if (egrid > 2048) egrid = 2048;
    int pgrid = (N + 3) / 4;     // 4 waves / block, one node per wave
    int nb = (N + 1023) / 1024;  // scan blocks
    int ggrid = (N + 63) / 64;   // mfma gemm blocks

    detect_kernel<<<1, 1024, 0, stream>>>((const int*)ei, flag);
    convert_kernel<<<egrid, 256, 0, stream>>>(ei, E, flag, rowi, coli, count);
    bsum_kernel<<<nb, 256, 0, stream>>>(count, bsum, N);
    scanb_kernel<<<1, 1024, 0, stream>>>(bsum, nb);
    emit_kernel<<<nb, 256, 0, stream>>>(count, bsum, base, dinv, N);
    scatter_kernel<<<egrid, 256, 0, stream>>>(rowi, coli, base, cursor, dinv, esrc2, E);
    wtrans_kernel<<<64, 256, 0, stream>>>(gcn_w, WT1);
    wtrans_kernel<<<64, 256, 0, stream>>>(dcn_w, WT2);

    ushort* Abf = (ushort*)A;

    gemm_mfma_kernel<<<ggrid, 256, 0, stream>>>(x, WT1, Abf, N);
    prop_kernel<<<pgrid, 256, 0, stream>>>((const unsigned*)Abf, base, count, esrc2, dinv, B, N);
    stats_kernel<<<1024, 256, 0, stream>>>(B, nullptr, sums1, sumsq1, N, 0);

    int agrid = (int)((N128 + 255) / 256);
    if (agrid > 4096) agrid = 4096;
    bnapply_kernel<<<agrid, 256, 0, stream>>>(B, sums1, sumsq1, bn1_g, bn1_b, H, N);

    gemm_mfma_kernel<<<ggrid, 256, 0, stream>>>(H, WT2, Abf, N);
    prop_kernel<<<pgrid, 256, 0, stream>>>((const unsigned*)Abf, base, count, esrc2, dinv, B, N);
    stats_kernel<<<1024, 256, 0, stream>>>(B, H, sums3, sumsq3, N, 1);

    final_kernel<<<pgrid, 256, 0, stream>>>(H, B, sums3, sumsq3, bn3_g, bn3_b,
                                            out_w, out_b, out, N);
}

// Round 7
// 212.257 us; speedup vs baseline: 2.2938x; 1.2838x over previous
//
#include <hip/hip_runtime.h>
#include <hip/hip_bf16.h>
#include <cstdint>

// ---------------------------------------------------------------------------
// DGNN pipeline, CSR-based aggregation (no scatter atomics on features).
// Biases gcn_b / dcn_b cancel inside the following batchnorms and are skipped.
// R2: multi-block scan. R3/R4: bf16 gather feed for prop (+4x unroll).
// R5: MFMA bf16 GEMM; scatter emits (src,dinv) pairs.
// R6: fusion round -- bnapply folded into gemm2 input-affine (BN1 is per-
//     channel affine; a1/b1 applied in-register); stats fused into both props
//     (LDS 4-wave reduce -> 64-slot partial atomics -> tiny reduce_ab kernel
//     that emits BN (a,b) directly); gate fused into prop2; detect inlined
//     into convert; both wtrans merged. 16 -> 14 launches, ~130MB less
//     streaming.
// ---------------------------------------------------------------------------

typedef __attribute__((ext_vector_type(8))) short bf16x8;
typedef __attribute__((ext_vector_type(4))) float f32x4;

__device__ __forceinline__ ushort f2bf(float f) {
    union { float f; unsigned u; } c; c.f = f;
    unsigned u = c.u;
    return (ushort)((u + 0x7fffu + ((u >> 16) & 1u)) >> 16);   // RNE
}
__device__ __forceinline__ float bflo(unsigned u) {
    union { unsigned i; float f; } c; c.i = u << 16; return c.f;
}
__device__ __forceinline__ float bfhi(unsigned u) {
    union { unsigned i; float f; } c; c.i = u & 0xffff0000u; return c.f;
}

// Detection inlined: for int64 input (values < 2^31) the odd int32 words are
// high-words == 0; for int32 input they are random node ids (P[all 4 zero]
// ~ (1/N)^4, negligible).
__global__ void convert_kernel(const void* __restrict__ ei, int E,
                               int* __restrict__ rowi, int* __restrict__ coli,
                               int* __restrict__ count) {
    const int* e32 = (const int*)ei;
    bool is64 = ((e32[1] | e32[3] | e32[5] | e32[7]) == 0);
    int stride = gridDim.x * blockDim.x;
    for (int e = blockIdx.x * blockDim.x + threadIdx.x; e < E; e += stride) {
        int r, c;
        if (is64) {
            r = (int)((const long long*)ei)[e];
            c = (int)((const long long*)ei)[E + e];
        } else {
            r = e32[e];
            c = e32[E + e];
        }
        rowi[e] = r;
        coli[e] = c;
        atomicAdd(&count[c], 1);
    }
}

// ---- 3-phase multi-block exclusive scan over count[N] ----
__global__ __launch_bounds__(256) void bsum_kernel(const int* __restrict__ count,
                                                   int* __restrict__ bsum, int n) {
    int t = threadIdx.x;
    int i0 = blockIdx.x * 1024 + t * 4;
    int s = 0;
    if (i0 + 4 <= n) {
        int4 v = *(const int4*)&count[i0];
        s = v.x + v.y + v.z + v.w;
    } else {
        for (int i = i0; i < n; i++) s += count[i];
    }
    __shared__ int ls[256];
    ls[t] = s;
    __syncthreads();
    for (int off = 128; off > 0; off >>= 1) {
        if (t < off) ls[t] += ls[t + off];
        __syncthreads();
    }
    if (t == 0) bsum[blockIdx.x] = ls[0];
}

__global__ void scanb_kernel(int* __restrict__ bsum, int nb) {
    __shared__ int sm[1024];
    int t = threadIdx.x;
    int v = (t < nb) ? bsum[t] : 0;
    sm[t] = v;
    __syncthreads();
    for (int off = 1; off < 1024; off <<= 1) {
        int a = (t >= off) ? sm[t - off] : 0;
        __syncthreads();
        sm[t] += a;
        __syncthreads();
    }
    if (t < nb) bsum[t] = sm[t] - v;   // exclusive
}

__global__ __launch_bounds__(256) void emit_kernel(const int* __restrict__ count,
                                                   const int* __restrict__ bbase,
                                                   int* __restrict__ base,
                                                   float* __restrict__ dinv, int n) {
    int t = threadIdx.x;
    int i0 = blockIdx.x * 1024 + t * 4;
    int v[4];
    int s = 0;
    if (i0 + 4 <= n) {
        int4 q = *(const int4*)&count[i0];
        v[0] = q.x; v[1] = q.y; v[2] = q.z; v[3] = q.w;
        s = v[0] + v[1] + v[2] + v[3];
    } else {
        #pragma unroll
        for (int k = 0; k < 4; k++) {
            int i = i0 + k;
            v[k] = (i < n) ? count[i] : 0;
            s += v[k];
        }
    }
    __shared__ int sm[256];
    sm[t] = s;
    __syncthreads();
    for (int off = 1; off < 256; off <<= 1) {
        int a = (t >= off) ? sm[t - off] : 0;
        __syncthreads();
        sm[t] += a;
        __syncthreads();
    }
    int run = bbase[blockIdx.x] + sm[t] - s;
    #pragma unroll
    for (int k = 0; k < 4; k++) {
        int i = i0 + k;
        if (i < n) {
            base[i] = run;
            dinv[i] = rsqrtf((float)(v[k] + 1));   // +1 self loop; always > 0
            run += v[k];
        }
    }
}

// Emit (src, dinv[src]) pairs per destination bucket.
__global__ void scatter_kernel(const int* __restrict__ rowi, const int* __restrict__ coli,
                               const int* __restrict__ base, int* __restrict__ cursor,
                               const float* __restrict__ dinv,
                               int2* __restrict__ esrc2, int E) {
    int stride = gridDim.x * blockDim.x;
    for (int e = blockIdx.x * blockDim.x + threadIdx.x; e < E; e += stride) {
        int c = coli[e];
        int r = rowi[e];
        int pos = base[c] + atomicAdd(&cursor[c], 1);
        int2 v;
        v.x = r;
        v.y = __float_as_int(dinv[r]);
        esrc2[pos] = v;
    }
}

// Both weight transposes in one launch: blocks [0,64) -> W1, [64,128) -> W2.
__global__ void wtrans_kernel(const float* __restrict__ W1, ushort* __restrict__ WT1,
                              const float* __restrict__ W2, ushort* __restrict__ WT2) {
    int b = blockIdx.x;
    const float* W = (b < 64) ? W1 : W2;
    ushort* WT = (b < 64) ? WT1 : WT2;
    int t = (b & 63) * 256 + threadIdx.x;
    int c = t >> 7, k = t & 127;
    WT[t] = f2bf(W[k * 128 + c]);
}

// Y[N][128] = bf16(affine(X)) @ bf16(W) via MFMA, output packed bf16.
// ab == nullptr: no input affine (gemm1). ab = [a[128], b[128]] applies
// h = a[k]*x[k]+b[k] in-register before rounding (BN1 folded into gemm2).
// Block: 4 waves x 16 rows. WT staged in LDS, pad stride 136.
// C/D mapping (HW-verified): col = lane&15, row = (lane>>4)*4 + reg.
__global__ __launch_bounds__(256) void gemm_mfma_kernel(const float* __restrict__ X,
                                                        const ushort* __restrict__ WT,
                                                        const float* __restrict__ ab,
                                                        ushort* __restrict__ Ybf, int n) {
    __shared__ ushort Wl[128 * 136];
    int t = threadIdx.x;
    for (int idx = t * 8; idx < 128 * 128; idx += 256 * 8) {
        int c = idx >> 7;
        int k = idx & 127;
        *(uint4*)&Wl[c * 136 + k] = *(const uint4*)&WT[idx];
    }
    __syncthreads();

    int wid = t >> 6;
    int lane = t & 63;
    int m0 = blockIdx.x * 64 + wid * 16;
    if (m0 >= n) return;                      // after the only barrier: safe
    int row = m0 + (lane & 15);
    int rc = row < n ? row : n - 1;           // clamp loads; stores predicated
    const float* xr = &X[(size_t)rc * 128];
    int kg = (lane >> 4) * 8;                 // k sub-offset: 0,8,16,24

    f32x4 acc[8];
    #pragma unroll
    for (int i = 0; i < 8; i++) acc[i] = (f32x4){0.f, 0.f, 0.f, 0.f};

    #pragma unroll
    for (int ks = 0; ks < 4; ks++) {
        int k0 = ks * 32 + kg;
        float4 lo = *(const float4*)&xr[k0];
        float4 hi = *(const float4*)&xr[k0 + 4];
        if (ab) {
            float4 alo = *(const float4*)&ab[k0];
            float4 ahi = *(const float4*)&ab[k0 + 4];
            float4 blo = *(const float4*)&ab[128 + k0];
            float4 bhi = *(const float4*)&ab[128 + k0 + 4];
            lo.x = alo.x * lo.x + blo.x; lo.y = alo.y * lo.y + blo.y;
            lo.z = alo.z * lo.z + blo.z; lo.w = alo.w * lo.w + blo.w;
            hi.x = ahi.x * hi.x + bhi.x; hi.y = ahi.y * hi.y + bhi.y;
            hi.z = ahi.z * hi.z + bhi.z; hi.w = ahi.w * hi.w + bhi.w;
        }
        bf16x8 a;
        a[0] = (short)f2bf(lo.x); a[1] = (short)f2bf(lo.y);
        a[2] = (short)f2bf(lo.z); a[3] = (short)f2bf(lo.w);
        a[4] = (short)f2bf(hi.x); a[5] = (short)f2bf(hi.y);
        a[6] = (short)f2bf(hi.z); a[7] = (short)f2bf(hi.w);
        #pragma unroll
        for (int nt = 0; nt < 8; nt++) {
            int c = nt * 16 + (lane & 15);
            bf16x8 b = *(bf16x8*)&Wl[c * 136 + k0];
            acc[nt] = __builtin_amdgcn_mfma_f32_16x16x32_bf16(a, b, acc[nt], 0, 0, 0);
        }
    }

    int ro = m0 + (lane >> 4) * 4;
    int co = lane & 15;
    #pragma unroll
    for (int nt = 0; nt < 8; nt++) {
        #pragma unroll
        for (int i = 0; i < 4; i++) {
            int r = ro + i;
            if (r < n) Ybf[(size_t)r * 128 + nt * 16 + co] = f2bf(acc[nt][i]);
        }
    }
}

// One wave per node. agg = dinv[n]*( sum_src w_src*XW[src] + dinv[n]*XW[n] ).
// gate==0: v = agg (GCN layer output pre-BN).
// gate==1: h = a1*B1[n]+b1 (BN1 affine); v = agg*h (DegGNN gate).
// Writes v; accumulates per-channel sum/sumsq partials (4-wave LDS reduce,
// then 4 atomics/lane into 64-slot partial arrays -> no address hot-spot).
__global__ __launch_bounds__(256) void prop_kernel(const unsigned* __restrict__ XWb,
                            const int* __restrict__ base,
                            const int* __restrict__ count, const int2* __restrict__ esrc2,
                            const float* __restrict__ dinv,
                            const float* __restrict__ B1, const float* __restrict__ ab1,
                            float* __restrict__ out,
                            float* __restrict__ psum, float* __restrict__ psq,
                            int n, int gate) {
    int wave = (int)((blockIdx.x * blockDim.x + threadIdx.x) >> 6);
    int lane = threadIdx.x & 63;
    int wid = threadIdx.x >> 6;
    float vx = 0.f, vy = 0.f;
    if (wave < n) {
        int b = base[wave];
        int cnt = count[wave];
        float din = dinv[wave];
        float accx = 0.f, accy = 0.f;
        int i = 0;
        for (; i + 4 <= cnt; i += 4) {
            int2 p0 = esrc2[b + i];
            int2 p1 = esrc2[b + i + 1];
            int2 p2 = esrc2[b + i + 2];
            int2 p3 = esrc2[b + i + 3];
            unsigned v0 = XWb[(size_t)p0.x * 64 + lane];
            unsigned v1 = XWb[(size_t)p1.x * 64 + lane];
            unsigned v2 = XWb[(size_t)p2.x * 64 + lane];
            unsigned v3 = XWb[(size_t)p3.x * 64 + lane];
            float w0 = __int_as_float(p0.y), w1 = __int_as_float(p1.y);
            float w2 = __int_as_float(p2.y), w3 = __int_as_float(p3.y);
            accx += w0 * bflo(v0); accy += w0 * bfhi(v0);
            accx += w1 * bflo(v1); accy += w1 * bfhi(v1);
            accx += w2 * bflo(v2); accy += w2 * bfhi(v2);
            accx += w3 * bflo(v3); accy += w3 * bfhi(v3);
        }
        for (; i < cnt; i++) {
            int2 p = esrc2[b + i];
            float w = __int_as_float(p.y);
            unsigned v = XWb[(size_t)p.x * 64 + lane];
            accx += w * bflo(v);
            accy += w * bfhi(v);
        }
        unsigned vs = XWb[(size_t)wave * 64 + lane];
        accx = din * (accx + din * bflo(vs));
        accy = din * (accy + din * bfhi(vs));
        if (gate) {
            int c0 = 2 * lane;
            float2 b1v = ((const float2*)B1)[(size_t)wave * 64 + lane];
            float2 a2 = *(const float2*)&ab1[c0];
            float2 bb2 = *(const float2*)&ab1[128 + c0];
            float h0 = a2.x * b1v.x + bb2.x;
            float h1 = a2.y * b1v.y + bb2.y;
            vx = accx * h0;
            vy = accy * h1;
        } else {
            vx = accx;
            vy = accy;
        }
        float2 o; o.x = vx; o.y = vy;
        ((float2*)out)[(size_t)wave * 64 + lane] = o;
    }
    // fused per-channel stats
    __shared__ float4 sm[4][64];
    float4 st; st.x = vx; st.y = vx * vx; st.z = vy; st.w = vy * vy;
    sm[wid][lane] = st;
    __syncthreads();
    if (threadIdx.x < 64) {
        float4 a0 = sm[0][lane], a1 = sm[1][lane], a2 = sm[2][lane], a3 = sm[3][lane];
        float s0 = a0.x + a1.x + a2.x + a3.x;
        float q0 = a0.y + a1.y + a2.y + a3.y;
        float s1 = a0.z + a1.z + a2.z + a3.z;
        float q1 = a0.w + a1.w + a2.w + a3.w;
        int slot = (blockIdx.x & 63) * 128;
        int c0 = 2 * lane;
        atomicAdd(&psum[slot + c0], s0);
        atomicAdd(&psq[slot + c0], q0);
        atomicAdd(&psum[slot + c0 + 1], s1);
        atomicAdd(&psq[slot + c0 + 1], q1);
    }
}

// Collapse 64-slot partials into BN affine coefficients: ab[c]=a, ab[128+c]=b.
__global__ void reduce_ab_kernel(const float* __restrict__ psum, const float* __restrict__ psq,
                                 const float* __restrict__ g, const float* __restrict__ beta,
                                 float* __restrict__ ab, int n) {
    int c = threadIdx.x;   // 128 threads
    float s = 0.f, s2 = 0.f;
    for (int r = 0; r < 64; r++) {
        s += psum[r * 128 + c];
        s2 += psq[r * 128 + c];
    }
    float invn = 1.f / (float)n;
    float mu = s * invn;
    float var = s2 * invn - mu * mu;
    float a = g[c] * rsqrtf(var + 1e-5f);
    ab[c] = a;
    ab[128 + c] = beta[c] - mu * a;
}

// result[n] = dot(h[n], ow[0:128]) + dot(BN3(gated[n]), ow[128:256]) + ob
// h computed on the fly from B1 via ab1; BN3 via ab3.
__global__ void final_kernel(const float* __restrict__ B1, const float* __restrict__ B2,
                             const float* __restrict__ ab1, const float* __restrict__ ab3,
                             const float* __restrict__ ow, const float* __restrict__ ob,
                             float* __restrict__ out, int n) {
    int wave = (int)((blockIdx.x * blockDim.x + threadIdx.x) >> 6);
    int lane = threadIdx.x & 63;
    if (wave >= n) return;
    int c0 = 2 * lane, c1 = c0 + 1;
    float2 b1v = ((const float2*)B1)[(size_t)wave * 64 + lane];
    float2 b2v = ((const float2*)B2)[(size_t)wave * 64 + lane];
    float h0 = ab1[c0] * b1v.x + ab1[128 + c0];
    float h1 = ab1[c1] * b1v.y + ab1[128 + c1];
    float o0 = ab3[c0] * b2v.x + ab3[128 + c0];
    float o1 = ab3[c1] * b2v.y + ab3[128 + c1];
    float partial = h0 * ow[c0] + h1 * ow[c1] + o0 * ow[128 + c0] + o1 * ow[128 + c1];
    #pragma unroll
    for (int off = 32; off > 0; off >>= 1) partial += __shfl_down(partial, off);
    if (lane == 0) out[wave] = partial + ob[0];
}

extern "C" void kernel_launch(void* const* d_in, const int* in_sizes, int n_in,
                              void* d_out, int out_size, void* d_ws, size_t ws_size,
                              hipStream_t stream) {
    const float* x     = (const float*)d_in[0];
    const void*  ei    = d_in[1];
    const float* gcn_w = (const float*)d_in[2];
    const float* bn1_g = (const float*)d_in[4];
    const float* bn1_b = (const float*)d_in[5];
    const float* dcn_w = (const float*)d_in[6];
    const float* bn3_g = (const float*)d_in[8];
    const float* bn3_b = (const float*)d_in[9];
    const float* out_w = (const float*)d_in[10];
    const float* out_b = (const float*)d_in[11];
    float* out = (float*)d_out;

    int N = in_sizes[0] / 128;
    int E = in_sizes[1] / 2;
    size_t N128 = (size_t)N * 128;

    float* A     = (float*)d_ws;            // bf16 xw/hw packed  [N*128 floats reserved]
    float* B1    = A + N128;                // GCN agg (pre-BN)   [N*128]
    float* B2    = B1 + N128;               // gated DegGNN out   [N*128]
    int*   rowi  = (int*)(B2 + N128);       // [E]
    int*   coli  = rowi + E;                // [E]
    int2*  esrc2 = (int2*)(coli + E);       // [E] (src, dinv[src])
    float* dinv  = (float*)(esrc2 + E);     // [N]
    int*   base  = (int*)(dinv + N);        // [N]
    int*   bsum  = base + N;                // [1024]
    ushort* WT1  = (ushort*)(bsum + 1024);  // [16384] bf16 gcn_w^T
    ushort* WT2  = WT1 + 16384;             // [16384] bf16 dcn_w^T
    float* ab1   = (float*)(WT2 + 16384);   // [256] BN1 a|b
    float* ab3   = ab1 + 256;               // [256] BN3 a|b
    // ---- zeroed region starts here ----
    int*   count  = (int*)(ab3 + 256);      // [N]
    int*   cursor = count + N;              // [N]
    float* psum1  = (float*)(cursor + N);   // [64*128]
    float* psq1   = psum1 + 8192;           // [64*128]
    float* psum3  = psq1 + 8192;            // [64*128]
    float* psq3   = psum3 + 8192;           // [64*128]

    size_t zero_bytes = (size_t)((char*)(psq3 + 8192) - (char*)count);
    (void)hipMemsetAsync(count, 0, zero_bytes, stream);

    int egrid = (E + 255) / 256;
    if (egrid > 2048) egrid = 2048;
    int pgrid = (N + 3) / 4;     // 4 waves / block, one node per wave
    int nb = (N + 1023) / 1024;  // scan blocks
    int ggrid = (N + 63) / 64;   // mfma gemm blocks

    convert_kernel<<<egrid, 256, 0, stream>>>(ei, E, rowi, coli, count);
    bsum_kernel<<<nb, 256, 0, stream>>>(count, bsum, N);
    scanb_kernel<<<1, 1024, 0, stream>>>(bsum, nb);
    emit_kernel<<<nb, 256, 0, stream>>>(count, bsum, base, dinv, N);
    scatter_kernel<<<egrid, 256, 0, stream>>>(rowi, coli, base, cursor, dinv, esrc2, E);
    wtrans_kernel<<<128, 256, 0, stream>>>(gcn_w, WT1, dcn_w, WT2);

    ushort* Abf = (ushort*)A;

    gemm_mfma_kernel<<<ggrid, 256, 0, stream>>>(x, WT1, nullptr, Abf, N);
    prop_kernel<<<pgrid, 256, 0, stream>>>((const unsigned*)Abf, base, count, esrc2, dinv,
                                           nullptr, nullptr, B1, psum1, psq1, N, 0);
    reduce_ab_kernel<<<1, 128, 0, stream>>>(psum1, psq1, bn1_g, bn1_b, ab1, N);

    gemm_mfma_kernel<<<ggrid, 256, 0, stream>>>(B1, WT2, ab1, Abf, N);
    prop_kernel<<<pgrid, 256, 0, stream>>>((const unsigned*)Abf, base, count, esrc2, dinv,
                                           B1, ab1, B2, psum3, psq3, N, 1);
    reduce_ab_kernel<<<1, 128, 0, stream>>>(psum3, psq3, bn3_g, bn3_b, ab3, N);

    final_kernel<<<pgrid, 256, 0, stream>>>(B1, B2, ab1, ab3, out_w, out_b, out, N);
}